// Round 11
// baseline (519.171 us; speedup 1.0000x reference)
//
#include <hip/hip_runtime.h>
#include <hip/hip_bf16.h>
#include <stdint.h>

typedef __attribute__((ext_vector_type(8))) short bv8;   // 8 x bf16 (MFMA A/B frag)
typedef __attribute__((ext_vector_type(4))) short sv4;   // 4 x bf16
typedef __attribute__((ext_vector_type(4))) float f4;    // MFMA C/D frag
typedef __attribute__((ext_vector_type(4))) unsigned uv4;

#define LDS_AS __attribute__((address_space(3)))
#define GLB_AS __attribute__((address_space(1)))

#if __has_builtin(__builtin_amdgcn_exp2f)
#define EXP2F(x) __builtin_amdgcn_exp2f(x)
#else
#define EXP2F(x) exp2f(x)
#endif

#define GBAR __builtin_amdgcn_s_barrier()

__device__ __forceinline__ void gload16(const void* g, void* l) {
  __builtin_amdgcn_global_load_lds((GLB_AS void*)(g), (LDS_AS void*)(l), 16, 0, 0);
}

__device__ __forceinline__ short f2bs(float x) {
  return __builtin_bit_cast(short, __float2bfloat16(x));
}
__device__ __forceinline__ float bs2f(short s) {
  unsigned u = ((unsigned)(unsigned short)s) << 16;
  return __builtin_bit_cast(float, u);
}
__device__ __forceinline__ unsigned cvtpk(float lo, float hi) {
  unsigned r;
  asm("v_cvt_pk_bf16_f32 %0, %1, %2" : "=v"(r) : "v"(lo), "v"(hi));
  return r;
}

// ---------------- fused prep: x cvt + all 6 weight transposes in ONE launch ----------------
__global__ __launch_bounds__(256) void k_prep(const float* __restrict__ x, short* __restrict__ xb,
                                              const float* __restrict__ Wq, short* __restrict__ Wqt,
                                              const float* __restrict__ Wk, short* __restrict__ Wkt,
                                              const float* __restrict__ Wv, short* __restrict__ Wvt,
                                              const float* __restrict__ Wo, short* __restrict__ Wot,
                                              const float* __restrict__ W1, short* __restrict__ W1t,
                                              const float* __restrict__ W2, short* __restrict__ W2t) {
  const int bid = blockIdx.x;
  if (bid < 8192) {
    const int i = (bid * 256 + threadIdx.x) * 4;
    const float4 v = *(const float4*)(x + i);
    sv4 o; o[0] = f2bs(v.x); o[1] = f2bs(v.y); o[2] = f2bs(v.z); o[3] = f2bs(v.w);
    *(sv4*)(xb + i) = o;
    return;
  }
  const float* W; short* Wt; int K, N, l;
  if (bid < 12288) {
    l = (bid - 8192) & 1023; K = 1024; N = 1024;
    const int sel = (bid - 8192) >> 10;
    W  = sel == 0 ? Wq  : sel == 1 ? Wk  : sel == 2 ? Wv  : Wo;
    Wt = sel == 0 ? Wqt : sel == 1 ? Wkt : sel == 2 ? Wvt : Wot;
  } else if (bid < 16384) {
    l = bid - 12288; K = 1024; N = 4096; W = W1; Wt = W1t;
  } else {
    l = bid - 16384; K = 4096; N = 1024; W = W2; Wt = W2t;
  }
  const int nb = N >> 5;
  const int n0 = (l % nb) * 32, k0 = (l / nb) * 32;
  __shared__ float tile[32][33];
  const int tx = threadIdx.x & 31, ty = threadIdx.x >> 5;
#pragma unroll
  for (int i = 0; i < 32; i += 8)
    tile[ty + i][tx] = W[(size_t)(k0 + ty + i) * N + n0 + tx];
  __syncthreads();
#pragma unroll
  for (int i = 0; i < 32; i += 8)
    Wt[(size_t)(n0 + ty + i) * K + k0 + tx] = f2bs(tile[tx][ty + i]);
}

// ======== 8-phase GEMM (T2+T3+T4+T5): BMxBN tile, BN=256, BM=MIH*64 ========
// EPI: 0 plain bf16, 1 relu bf16, 2 QKV (sel uniform per block; V-blocks flush via
// LDS transpose -> coalesced 16B stores instead of 2B stride-4KB scatter).
template<int EPI, int MIH>
__global__ __launch_bounds__(512) void k_gemm8p(
    const short* __restrict__ A, const short* __restrict__ Bt,
    const float* __restrict__ bias, const float* __restrict__ bias2, const float* __restrict__ bias3,
    short* __restrict__ C, short* __restrict__ D2, short* __restrict__ D3,
    int M, int N, int K, int nbx) {
  constexpr int BM = MIH * 64;
  constexpr int HOFF = (MIH == 4) ? 16384 : 4096;
  constexpr int SBOFF = 2 * BM * 128;               // bytes: SA region size
  __shared__ __align__(16) char LDSBUF[SBOFF + 65536];

  const int t = threadIdx.x;
  const int lane = t & 63, w = t >> 6;
  const int wr = w >> 2, wc = w & 3;
  const int lr = lane & 15, lg = lane >> 4;
  const int cpx = gridDim.x >> 3;
  const int bid = blockIdx.x;
  const int wid = (bid & 7) * cpx + (bid >> 3);
  const int by = wid / nbx, bx = wid % nbx;
  const int m0 = by * BM, n0 = bx * 256;
  const int nt = K >> 6;
  const int swz = ((t >> 3) & 7) << 4;
  const int rbyte0 = (lg * 16) ^ ((lr & 7) << 4);
  const int rbyte1 = (64 + lg * 16) ^ ((lr & 7) << 4);

  auto SAb = [&](int buf) -> char* { return LDSBUF + buf * (BM * 128); };
  auto SBb = [&](int buf) -> char* { return LDSBUF + SBOFF + buf * 32768; };

  auto ST_A = [&](int k0, int half, int buf) {
#pragma unroll
    for (int i = 0; i < 2; ++i) {
      const int L = t * 16 + i * 8192;
      const int cbs = (L & 127) ^ swz;
      const int grow = (MIH == 4) ? (m0 + i * 128 + half * 64 + (t >> 3))
                                  : (m0 + i * 64 + (t >> 3));
      gload16(A + (size_t)grow * K + k0 + (cbs >> 1),
              SAb(buf) + (MIH == 4 ? half * 16384 : 0) + L);
    }
  };
  auto ST_B = [&](int k0, int half, int buf) {
#pragma unroll
    for (int i = 0; i < 2; ++i) {
      const int L = t * 16 + i * 8192;
      const int rr = (t >> 3) + i * 64;
      const int cbs = (L & 127) ^ swz;
      const int grow = n0 + (rr >> 5) * 64 + half * 32 + (rr & 31);
      gload16(Bt + (size_t)grow * K + k0 + (cbs >> 1),
              SBb(buf) + half * 16384 + L);
    }
  };

  f4 acc[2 * MIH][4] = {};
  bv8 af[MIH][2], bflo[2][2], bfhi[2][2];

  auto LDA = [&](int buf, int half) {
    const char* base = SAb(buf) + half * HOFF + wr * 8192;
#pragma unroll
    for (int m = 0; m < MIH; ++m) {
      af[m][0] = *(const bv8*)(base + (m * 16 + lr) * 128 + rbyte0);
      af[m][1] = *(const bv8*)(base + (m * 16 + lr) * 128 + rbyte1);
    }
  };
  auto LDB = [&](int buf, int half, bv8 (&bf)[2][2]) {
    const char* base = SBb(buf) + half * 16384 + wc * 4096;
#pragma unroll
    for (int n = 0; n < 2; ++n) {
      bf[n][0] = *(const bv8*)(base + (n * 16 + lr) * 128 + rbyte0);
      bf[n][1] = *(const bv8*)(base + (n * 16 + lr) * 128 + rbyte1);
    }
  };
  auto MM = [&](bv8 (&bf)[2][2], int mB, int nB) {
    __builtin_amdgcn_s_setprio(1);
#pragma unroll
    for (int kk = 0; kk < 2; ++kk)
#pragma unroll
      for (int m = 0; m < MIH; ++m)
#pragma unroll
        for (int n = 0; n < 2; ++n)
          acc[mB + m][nB + n] = __builtin_amdgcn_mfma_f32_16x16x32_bf16(
              af[m][kk], bf[n][kk], acc[mB + m][nB + n], 0, 0, 0);
    __builtin_amdgcn_s_setprio(0);
  };

  ST_A(0, 0, 0); if (MIH == 4) ST_A(0, 1, 0);
  ST_B(0, 0, 0); ST_B(0, 1, 0);
  ST_A(64, 0, 1);
  ST_B(64, 1, 1);
  if (MIH == 4) { ST_A(64, 1, 1); asm volatile("s_waitcnt vmcnt(6)" ::: "memory"); }
  else          { asm volatile("s_waitcnt vmcnt(4)" ::: "memory"); }
  GBAR;

  const int nIter = nt >> 1;
  for (int it = 0; it < nIter; ++it) {
    const int k1 = (2 * it + 1) << 6;
    const int k2 = (2 * it + 2) << 6, k3 = (2 * it + 3) << 6;
    const bool h2 = (2 * it + 2) < nt, h3 = (2 * it + 3) < nt;

    LDA(0, 0); LDB(0, 0, bflo);
    ST_B(k1, 0, 1);
    GBAR; MM(bflo, 0, 0); GBAR;
    LDB(0, 1, bfhi);
    if (h2 && MIH == 4) ST_A(k2, 0, 0);
    GBAR; MM(bfhi, 0, 2); GBAR;
    LDA(0, 1);
    if (h2) ST_B(k2, 1, 0);
    GBAR; MM(bfhi, MIH, 2); GBAR;
    if (h2) ST_A(k2, (MIH == 4) ? 1 : 0, 0);
    if (h2) {
      if (MIH == 4) asm volatile("s_waitcnt vmcnt(6)" ::: "memory");
      else          asm volatile("s_waitcnt vmcnt(4)" ::: "memory");
    } else {
      asm volatile("s_waitcnt vmcnt(0)" ::: "memory");
    }
    GBAR; MM(bflo, MIH, 0); GBAR;

    LDA(1, 0); LDB(1, 0, bflo);
    if (h2) ST_B(k2, 0, 0);
    GBAR; MM(bflo, 0, 0); GBAR;
    LDB(1, 1, bfhi);
    if (h3 && MIH == 4) ST_A(k3, 0, 1);
    GBAR; MM(bfhi, 0, 2); GBAR;
    LDA(1, 1);
    if (h3) ST_B(k3, 1, 1);
    GBAR; MM(bfhi, MIH, 2); GBAR;
    if (h3) ST_A(k3, (MIH == 4) ? 1 : 0, 1);
    if (h3) {
      if (MIH == 4) asm volatile("s_waitcnt vmcnt(6)" ::: "memory");
      else          asm volatile("s_waitcnt vmcnt(4)" ::: "memory");
    } else {
      asm volatile("s_waitcnt vmcnt(0)" ::: "memory");
    }
    GBAR; MM(bflo, MIH, 0); GBAR;
  }

  // ---------------- epilogue ----------------
  if (EPI == 2 && (n0 >> 10) == 2) {
    // V block (uniform): bias-add, then LDS transpose [d][s] (pad 136) -> coalesced flush
    short* TR = (short*)LDSBUF;
    __syncthreads();
#pragma unroll
    for (int ni = 0; ni < 4; ++ni) {
      const int dloc = wc * 64 + ni * 16 + lr;          // 0..255
      const float bvs = bias3[(n0 - 2048) + dloc];
#pragma unroll
      for (int mi = 0; mi < 2 * MIH; ++mi) {
        const int sloc = wr * (MIH * 32) + mi * 16 + lg * 4;  // 0..BM-4
        sv4 pk;
#pragma unroll
        for (int j = 0; j < 4; ++j) pk[j] = f2bs(acc[mi][ni][j] + bvs);
        *(sv4*)(TR + dloc * 136 + sloc) = pk;           // b64, ~2-4 way conflicts (epilogue-only)
      }
    }
    __syncthreads();
    const int bb = m0 >> 11, s0r = m0 & 2047;
    const int dd = t >> 1, sh = (t & 1) * 64;           // 512 thr -> 256 rows x 2 halves
    const int dg = (n0 - 2048) + dd;
    const int hh = dg >> 6, dl = dg & 63;
    short* dst = D3 + ((size_t)(bb * 16 + hh) * 64 + dl) * 2048 + s0r + sh;
    if (MIH == 2) {                                      // BM=128: halves are 64 shorts
#pragma unroll
      for (int i = 0; i < 8; ++i)
        *(bv8*)(dst + i * 8) = *(const bv8*)(TR + dd * 136 + sh + i * 8);
    }
    return;
  }

#pragma unroll
  for (int ni = 0; ni < 4; ++ni) {
    const int c = n0 + wc * 64 + ni * 16 + lr;
    float bvs;
    int sel = 0, h = 0, d = 0;
    if (EPI == 2) {
      sel = c >> 10; const int cc = c & 1023;
      bvs = (sel == 0 ? bias : bias2)[cc];
      h = cc >> 6; d = cc & 63;
    } else {
      bvs = bias[c];
    }
#pragma unroll
    for (int mi = 0; mi < 2 * MIH; ++mi) {
#pragma unroll
      for (int j = 0; j < 4; ++j) {
        const int r = m0 + wr * (MIH * 32) + mi * 16 + lg * 4 + j;
        float v = acc[mi][ni][j] + bvs;
        if (EPI == 1) v = fmaxf(v, 0.f);
        if (EPI == 2) {
          const int bb = r >> 11, s = r & 2047;
          if (sel == 0) C [((size_t)(bb * 16 + h) * 2048 + s) * 64 + d] = f2bs(v);
          else          D2[((size_t)(bb * 16 + h) * 2048 + s) * 64 + d] = f2bs(v);
        } else {
          C[(size_t)r * N + c] = f2bs(v);
        }
      }
    }
  }
}

// ---------------- flash attention: in-reg P + 1-tile-deep V prefetch ----------------
// vfA for tile t+1 issued after QKSM(1) of tile t (covered by PV(vfB)+barrier+stage+QKSM(0));
// vfB issued before PV(vfA) (covered by PV(vfA)+QKSM(1)). Same register budget as R10.
__global__ __launch_bounds__(256) void k_attn(const short* __restrict__ Qg, const short* __restrict__ Kg,
                                              const short* __restrict__ Vtg, short* __restrict__ Oc) {
  __shared__ __align__(16) short Ks[2][128 * 64];  // dbuf [s][dk] swizzled, 128B rows

  const int t = threadIdx.x, lane = t & 63, w = t >> 6;
  const int lr = lane & 15, lg = lane >> 4;
  const int bid = blockIdx.x;
  const int wid = (bid & 7) * 128 + (bid >> 3);
  const int q0 = (wid & 15) * 128;
  const int bh = wid >> 4;
  const int b = bh >> 4, h = bh & 15;
  const short* Qp = Qg + (size_t)bh * 2048 * 64;
  const short* Kp = Kg + (size_t)bh * 2048 * 64;
  const short* Vp = Vtg + (size_t)bh * 64 * 2048;

  bv8 qf[2][2];
#pragma unroll
  for (int mi = 0; mi < 2; ++mi)
#pragma unroll
    for (int kk = 0; kk < 2; ++kk)
      qf[mi][kk] = *(const bv8*)(Qp + (size_t)(q0 + w * 32 + mi * 16 + lr) * 64 + kk * 32 + lg * 8);

  f4 Oa[2][4] = {};
  float lsum[2] = {0.f, 0.f};
  const float SC = 0.125f * 1.44269504089f;
  const bool hi = lg >= 2;
  const bool xx = (lg == 1) || (lg == 2);

  auto QKSM = [&](const char* Kb, int hf, bv8 (&pf)[2][2]) {
    f4 Sa[2][4] = {};
#pragma unroll
    for (int kk = 0; kk < 2; ++kk) {
      bv8 kf[4];
#pragma unroll
      for (int nl = 0; nl < 4; ++nl) {
        const int row = (hf * 4 + nl) * 16 + lr;
        const int cb = kk * 64 + lg * 16;
        kf[nl] = *(const bv8*)(Kb + row * 128 + (cb ^ ((row & 7) << 4)));
      }
      __builtin_amdgcn_s_setprio(1);
#pragma unroll
      for (int mi = 0; mi < 2; ++mi)
#pragma unroll
        for (int nl = 0; nl < 4; ++nl)
          Sa[mi][nl] = __builtin_amdgcn_mfma_f32_16x16x32_bf16(kf[nl], qf[mi][kk], Sa[mi][nl], 0, 0, 0);
      __builtin_amdgcn_s_setprio(0);
    }
#pragma unroll
    for (int mi = 0; mi < 2; ++mi) {
      float rs = 0.f;
#pragma unroll
      for (int nl = 0; nl < 4; ++nl)
#pragma unroll
        for (int j = 0; j < 4; ++j) {
          const float p = EXP2F(Sa[mi][nl][j] * SC);
          Sa[mi][nl][j] = p;
          rs += p;
        }
      lsum[mi] += rs;
    }
#pragma unroll
    for (int k2 = 0; k2 < 2; ++k2)
#pragma unroll
      for (int mi = 0; mi < 2; ++mi) {
        const unsigned W0 = cvtpk(Sa[mi][2 * k2][0], Sa[mi][2 * k2][1]);
        const unsigned W1 = cvtpk(Sa[mi][2 * k2][2], Sa[mi][2 * k2][3]);
        const unsigned W2 = cvtpk(Sa[mi][2 * k2 + 1][0], Sa[mi][2 * k2 + 1][1]);
        const unsigned W3 = cvtpk(Sa[mi][2 * k2 + 1][2], Sa[mi][2 * k2 + 1][3]);
        const unsigned w0 = hi ? W2 : W0, w1 = hi ? W3 : W1;
        const unsigned s0 = __shfl_xor(hi ? W0 : W2, 32);
        const unsigned s1 = __shfl_xor(hi ? W1 : W3, 32);
        const unsigned t0 = __shfl_xor(xx ? w0 : s0, 16);
        const unsigned t1 = __shfl_xor(xx ? w1 : s1, 16);
        uv4 u;
        u[0] = (lg == 0) ? w0 : (lg == 2) ? s0 : t0;
        u[1] = (lg == 0) ? w1 : (lg == 2) ? s1 : t1;
        u[2] = (lg == 3) ? w0 : (lg == 1) ? s0 : t0;
        u[3] = (lg == 3) ? w1 : (lg == 1) ? s1 : t1;
        pf[k2][mi] = __builtin_bit_cast(bv8, u);
      }
  };
  auto LOADV = [&](int kt, int hf, bv8 (&vf)[2][4]) {
#pragma unroll
    for (int k2 = 0; k2 < 2; ++k2)
#pragma unroll
      for (int nO = 0; nO < 4; ++nO)
        vf[k2][nO] = *(const bv8*)(Vp + (size_t)(nO * 16 + lr) * 2048 + kt + hf * 64 + k2 * 32 + lg * 8);
  };
  auto PV = [&](bv8 (&vf)[2][4], bv8 (&pf)[2][2]) {
    __builtin_amdgcn_s_setprio(1);
#pragma unroll
    for (int k2 = 0; k2 < 2; ++k2)
#pragma unroll
      for (int mi = 0; mi < 2; ++mi)
#pragma unroll
        for (int nO = 0; nO < 4; ++nO)
          Oa[mi][nO] = __builtin_amdgcn_mfma_f32_16x16x32_bf16(vf[k2][nO], pf[k2][mi], Oa[mi][nO], 0, 0, 0);
    __builtin_amdgcn_s_setprio(0);
  };

#pragma unroll
  for (int i = 0; i < 4; ++i) {
    const int L = t * 16 + i * 4096;
    const int row = L >> 7;
    const int cbs = (L & 127) ^ ((row & 7) << 4);
    gload16(Kp + (size_t)row * 64 + (cbs >> 1), (char*)Ks[0] + L);
  }
  bv8 vfA[2][4], vfB[2][4];
  LOADV(0, 0, vfA);          // prologue: V(tile0, half0)
  __syncthreads();

  int cur = 0;
  for (int kt = 0; kt < 2048; kt += 128) {
    if (kt + 128 < 2048) {
#pragma unroll
      for (int i = 0; i < 4; ++i) {
        const int L = t * 16 + i * 4096;
        const int row = L >> 7;
        const int cbs = (L & 127) ^ ((row & 7) << 4);
        gload16(Kp + (size_t)(kt + 128 + row) * 64 + (cbs >> 1), (char*)Ks[cur ^ 1] + L);
      }
    }
    const char* Kb = (const char*)Ks[cur];

    bv8 pfA[2][2], pfB[2][2];
    QKSM(Kb, 0, pfA);          // vfA already in flight since last iteration
    LOADV(kt, 1, vfB);         // covered by PV(vfA)+QKSM(1)
    PV(vfA, pfA);
    QKSM(Kb, 1, pfB);
    if (kt + 128 < 2048) LOADV(kt + 128, 0, vfA);   // next tile's half0: max cover
    PV(vfB, pfB);

    __syncthreads();
    cur ^= 1;
  }

#pragma unroll
  for (int mi = 0; mi < 2; ++mi) {
    lsum[mi] += __shfl_xor(lsum[mi], 16);
    lsum[mi] += __shfl_xor(lsum[mi], 32);
  }

#pragma unroll
  for (int mi = 0; mi < 2; ++mi) {
    const float inv = 1.f / lsum[mi];
    const int q = q0 + w * 32 + mi * 16 + lr;
#pragma unroll
    for (int nO = 0; nO < 4; ++nO) {
      sv4 o;
#pragma unroll
      for (int j = 0; j < 4; ++j) o[j] = f2bs(Oa[mi][nO][j] * inv);
      const int c = h * 64 + nO * 16 + lg * 4;
      *(sv4*)(Oc + ((size_t)b * 2048 + q) * 1024 + c) = o;
    }
  }
}

// ---------------- residual + LayerNorm (mean, unbiased std, eps on std) ----------------
template<int MODE>
__global__ __launch_bounds__(256) void k_resnorm(const short* __restrict__ a, const void* __restrict__ res,
                                                 const float* __restrict__ alpha, const float* __restrict__ beta,
                                                 void* __restrict__ out) {
  const int row = blockIdx.x;
  const int t = threadIdx.x;
  const int lane = t & 63, w = t >> 6;
  const size_t base = (size_t)row * 1024;

  const sv4 av = *(const sv4*)(a + base + t * 4);
  float v[4];
  if (MODE == 0) {
    const float4 rv = *(const float4*)((const float*)res + base + t * 4);
    v[0] = bs2f(av[0]) + rv.x; v[1] = bs2f(av[1]) + rv.y;
    v[2] = bs2f(av[2]) + rv.z; v[3] = bs2f(av[3]) + rv.w;
  } else {
    const sv4 rv = *(const sv4*)((const short*)res + base + t * 4);
#pragma unroll
    for (int i = 0; i < 4; ++i) v[i] = bs2f(av[i]) + bs2f(rv[i]);
  }
  float s = v[0] + v[1] + v[2] + v[3];
  float sq = v[0] * v[0] + v[1] * v[1] + v[2] * v[2] + v[3] * v[3];
#pragma unroll
  for (int m = 1; m < 64; m <<= 1) { s += __shfl_xor(s, m); sq += __shfl_xor(sq, m); }
  __shared__ float red[8];
  if (lane == 0) { red[w] = s; red[w + 4] = sq; }
  __syncthreads();
  s = red[0] + red[1] + red[2] + red[3];
  sq = red[4] + red[5] + red[6] + red[7];
  const float mean = s * (1.f / 1024.f);
  const float var = (sq - 1024.f * mean * mean) * (1.f / 1023.f);   // ddof=1
  const float inv = 1.f / (sqrtf(fmaxf(var, 0.f)) + 1e-6f);          // eps added to std
  const float4 al = *(const float4*)(alpha + t * 4);
  const float4 be = *(const float4*)(beta + t * 4);
  float y[4];
  y[0] = al.x * (v[0] - mean) * inv + be.x;
  y[1] = al.y * (v[1] - mean) * inv + be.y;
  y[2] = al.z * (v[2] - mean) * inv + be.z;
  y[3] = al.w * (v[3] - mean) * inv + be.w;
  if (MODE == 0) {
    sv4 o; o[0] = f2bs(y[0]); o[1] = f2bs(y[1]); o[2] = f2bs(y[2]); o[3] = f2bs(y[3]);
    *(sv4*)((short*)out + base + t * 4) = o;
  } else {
    *(float4*)((float*)out + base + t * 4) = make_float4(y[0], y[1], y[2], y[3]);
  }
}

extern "C" void kernel_launch(void* const* d_in, const int* in_sizes, int n_in,
                              void* d_out, int out_size, void* d_ws, size_t ws_size,
                              hipStream_t stream) {
  const float* x   = (const float*)d_in[0];
  const float* Wq  = (const float*)d_in[1];
  const float* bq  = (const float*)d_in[2];
  const float* Wk  = (const float*)d_in[3];
  const float* bk  = (const float*)d_in[4];
  const float* Wv  = (const float*)d_in[5];
  const float* bv  = (const float*)d_in[6];
  const float* Wo  = (const float*)d_in[7];
  const float* bo  = (const float*)d_in[8];
  const float* al1 = (const float*)d_in[9];
  const float* bi1 = (const float*)d_in[10];
  const float* al2 = (const float*)d_in[11];
  const float* bi2 = (const float*)d_in[12];
  const float* W1  = (const float*)d_in[13];
  const float* b1  = (const float*)d_in[14];
  const float* W2  = (const float*)d_in[15];
  const float* b2  = (const float*)d_in[16];

  if (ws_size < (size_t)136 * 1024 * 1024) return;  // need 136MB scratch

  char* ws = (char*)d_ws;
  short* xb  = (short*)(ws);                   // 16MB, dead after QKV
  short* Qb  = (short*)(ws + (16ll << 20));    // 16MB
  short* Kb  = (short*)(ws + (32ll << 20));    // 16MB
  short* Vtb = (short*)(ws + (48ll << 20));    // 16MB
  short* Hb  = (short*)(ws);                   // 64MB: reuses xb+Q+K+Vt after attention
  short* Wqt = (short*)(ws + (64ll << 20));    // [3072][1024] contiguous with Wkt/Wvt
  short* Wkt = (short*)(ws + (66ll << 20));
  short* Wvt = (short*)(ws + (68ll << 20));
  short* Wot = (short*)(ws + (70ll << 20));
  short* W1t = (short*)(ws + (72ll << 20));    // 8MB
  short* W2t = (short*)(ws + (80ll << 20));    // 8MB
  short* Cc  = (short*)(ws + (88ll << 20));    // 16MB
  short* AOb = (short*)(ws + (104ll << 20));   // 16MB, reused for FFb
  short* N1b = (short*)(ws + (120ll << 20));   // 16MB
  short* FFb = (short*)(ws + (104ll << 20));

  // fused prep (1 launch replaces 7)
  k_prep<<<20480, 256, 0, stream>>>(x, xb, Wq, Wqt, Wk, Wkt, Wv, Wvt, Wo, Wot, W1, W1t, W2, W2t);

  // fused QKV: 8192x3072 @ K=1024, 128x256 tiles -> grid 768
  k_gemm8p<2, 2><<<768, 512, 0, stream>>>(xb, Wqt, bq, bk, bv, Qb, Kb, Vtb, 8192, 3072, 1024, 12);

  // attention -> concat
  k_attn<<<1024, 256, 0, stream>>>(Qb, Kb, Vtb, Cc);

  // output proj: 8192x1024, 128x256 tiles -> grid 256
  k_gemm8p<0, 2><<<256, 512, 0, stream>>>(Cc, Wot, bo, nullptr, nullptr, AOb, nullptr, nullptr,
                                          8192, 1024, 1024, 4);
  k_resnorm<0><<<8192, 256, 0, stream>>>(AOb, x, al1, bi1, N1b);

  // FFN1: 8192x4096 relu, 256x256 tiles -> grid 512
  k_gemm8p<1, 4><<<512, 512, 0, stream>>>(N1b, W1t, b1, nullptr, nullptr, Hb, nullptr, nullptr,
                                          8192, 4096, 1024, 16);
  // FFN2: 8192x1024 @ K=4096, 128x256 tiles -> grid 256
  k_gemm8p<0, 2><<<256, 512, 0, stream>>>(Hb, W2t, b2, nullptr, nullptr, FFb, nullptr, nullptr,
                                          8192, 1024, 4096, 4);
  k_resnorm<1><<<8192, 256, 0, stream>>>(FFb, N1b, al2, bi2, (float*)d_out);
}

// Round 12
// 411.210 us; speedup vs baseline: 1.2625x; 1.2625x over previous
//
#include <hip/hip_runtime.h>
#include <hip/hip_bf16.h>
#include <stdint.h>

typedef __attribute__((ext_vector_type(8))) short bv8;   // 8 x bf16 (MFMA A/B frag)
typedef __attribute__((ext_vector_type(4))) short sv4;   // 4 x bf16
typedef __attribute__((ext_vector_type(4))) float f4;    // MFMA C/D frag
typedef __attribute__((ext_vector_type(4))) unsigned uv4;

#define LDS_AS __attribute__((address_space(3)))
#define GLB_AS __attribute__((address_space(1)))

#if __has_builtin(__builtin_amdgcn_exp2f)
#define EXP2F(x) __builtin_amdgcn_exp2f(x)
#else
#define EXP2F(x) exp2f(x)
#endif

#define GBAR __builtin_amdgcn_s_barrier()

__device__ __forceinline__ void gload16(const void* g, void* l) {
  __builtin_amdgcn_global_load_lds((GLB_AS void*)(g), (LDS_AS void*)(l), 16, 0, 0);
}

__device__ __forceinline__ short f2bs(float x) {
  return __builtin_bit_cast(short, __float2bfloat16(x));
}
__device__ __forceinline__ float bs2f(short s) {
  unsigned u = ((unsigned)(unsigned short)s) << 16;
  return __builtin_bit_cast(float, u);
}
__device__ __forceinline__ unsigned cvtpk(float lo, float hi) {
  unsigned r;
  asm("v_cvt_pk_bf16_f32 %0, %1, %2" : "=v"(r) : "v"(lo), "v"(hi));
  return r;
}

// ---------------- fused prep: x cvt + all 6 weight transposes in ONE launch ----------------
__global__ __launch_bounds__(256) void k_prep(const float* __restrict__ x, short* __restrict__ xb,
                                              const float* __restrict__ Wq, short* __restrict__ Wqt,
                                              const float* __restrict__ Wk, short* __restrict__ Wkt,
                                              const float* __restrict__ Wv, short* __restrict__ Wvt,
                                              const float* __restrict__ Wo, short* __restrict__ Wot,
                                              const float* __restrict__ W1, short* __restrict__ W1t,
                                              const float* __restrict__ W2, short* __restrict__ W2t) {
  const int bid = blockIdx.x;
  if (bid < 8192) {
    const int i = (bid * 256 + threadIdx.x) * 4;
    const float4 v = *(const float4*)(x + i);
    sv4 o; o[0] = f2bs(v.x); o[1] = f2bs(v.y); o[2] = f2bs(v.z); o[3] = f2bs(v.w);
    *(sv4*)(xb + i) = o;
    return;
  }
  const float* W; short* Wt; int K, N, l;
  if (bid < 12288) {
    l = (bid - 8192) & 1023; K = 1024; N = 1024;
    const int sel = (bid - 8192) >> 10;
    W  = sel == 0 ? Wq  : sel == 1 ? Wk  : sel == 2 ? Wv  : Wo;
    Wt = sel == 0 ? Wqt : sel == 1 ? Wkt : sel == 2 ? Wvt : Wot;
  } else if (bid < 16384) {
    l = bid - 12288; K = 1024; N = 4096; W = W1; Wt = W1t;
  } else {
    l = bid - 16384; K = 4096; N = 1024; W = W2; Wt = W2t;
  }
  const int nb = N >> 5;
  const int n0 = (l % nb) * 32, k0 = (l / nb) * 32;
  __shared__ float tile[32][33];
  const int tx = threadIdx.x & 31, ty = threadIdx.x >> 5;
#pragma unroll
  for (int i = 0; i < 32; i += 8)
    tile[ty + i][tx] = W[(size_t)(k0 + ty + i) * N + n0 + tx];
  __syncthreads();
#pragma unroll
  for (int i = 0; i < 32; i += 8)
    Wt[(size_t)(n0 + ty + i) * K + k0 + tx] = f2bs(tile[tx][ty + i]);
}

// ======== 8-phase GEMM (T2+T3+T4+T5): BMxBN tile, BN=256, BM=MIH*64 ========
// EPI: 0 plain bf16, 1 relu bf16, 2 QKV (sel uniform per block; V-blocks flush via
// LDS transpose -> coalesced 16B stores instead of 2B stride-4KB scatter).
template<int EPI, int MIH>
__global__ __launch_bounds__(512) void k_gemm8p(
    const short* __restrict__ A, const short* __restrict__ Bt,
    const float* __restrict__ bias, const float* __restrict__ bias2, const float* __restrict__ bias3,
    short* __restrict__ C, short* __restrict__ D2, short* __restrict__ D3,
    int M, int N, int K, int nbx) {
  constexpr int BM = MIH * 64;
  constexpr int HOFF = (MIH == 4) ? 16384 : 4096;
  constexpr int SBOFF = 2 * BM * 128;               // bytes: SA region size
  __shared__ __align__(16) char LDSBUF[SBOFF + 65536];

  const int t = threadIdx.x;
  const int lane = t & 63, w = t >> 6;
  const int wr = w >> 2, wc = w & 3;
  const int lr = lane & 15, lg = lane >> 4;
  const int cpx = gridDim.x >> 3;
  const int bid = blockIdx.x;
  const int wid = (bid & 7) * cpx + (bid >> 3);
  const int by = wid / nbx, bx = wid % nbx;
  const int m0 = by * BM, n0 = bx * 256;
  const int nt = K >> 6;
  const int swz = ((t >> 3) & 7) << 4;
  const int rbyte0 = (lg * 16) ^ ((lr & 7) << 4);
  const int rbyte1 = (64 + lg * 16) ^ ((lr & 7) << 4);

  auto SAb = [&](int buf) -> char* { return LDSBUF + buf * (BM * 128); };
  auto SBb = [&](int buf) -> char* { return LDSBUF + SBOFF + buf * 32768; };

  auto ST_A = [&](int k0, int half, int buf) {
#pragma unroll
    for (int i = 0; i < 2; ++i) {
      const int L = t * 16 + i * 8192;
      const int cbs = (L & 127) ^ swz;
      const int grow = (MIH == 4) ? (m0 + i * 128 + half * 64 + (t >> 3))
                                  : (m0 + i * 64 + (t >> 3));
      gload16(A + (size_t)grow * K + k0 + (cbs >> 1),
              SAb(buf) + (MIH == 4 ? half * 16384 : 0) + L);
    }
  };
  auto ST_B = [&](int k0, int half, int buf) {
#pragma unroll
    for (int i = 0; i < 2; ++i) {
      const int L = t * 16 + i * 8192;
      const int rr = (t >> 3) + i * 64;
      const int cbs = (L & 127) ^ swz;
      const int grow = n0 + (rr >> 5) * 64 + half * 32 + (rr & 31);
      gload16(Bt + (size_t)grow * K + k0 + (cbs >> 1),
              SBb(buf) + half * 16384 + L);
    }
  };

  f4 acc[2 * MIH][4] = {};
  bv8 af[MIH][2], bflo[2][2], bfhi[2][2];

  auto LDA = [&](int buf, int half) {
    const char* base = SAb(buf) + half * HOFF + wr * 8192;
#pragma unroll
    for (int m = 0; m < MIH; ++m) {
      af[m][0] = *(const bv8*)(base + (m * 16 + lr) * 128 + rbyte0);
      af[m][1] = *(const bv8*)(base + (m * 16 + lr) * 128 + rbyte1);
    }
  };
  auto LDB = [&](int buf, int half, bv8 (&bf)[2][2]) {
    const char* base = SBb(buf) + half * 16384 + wc * 4096;
#pragma unroll
    for (int n = 0; n < 2; ++n) {
      bf[n][0] = *(const bv8*)(base + (n * 16 + lr) * 128 + rbyte0);
      bf[n][1] = *(const bv8*)(base + (n * 16 + lr) * 128 + rbyte1);
    }
  };
  auto MM = [&](bv8 (&bf)[2][2], int mB, int nB) {
    __builtin_amdgcn_s_setprio(1);
#pragma unroll
    for (int kk = 0; kk < 2; ++kk)
#pragma unroll
      for (int m = 0; m < MIH; ++m)
#pragma unroll
        for (int n = 0; n < 2; ++n)
          acc[mB + m][nB + n] = __builtin_amdgcn_mfma_f32_16x16x32_bf16(
              af[m][kk], bf[n][kk], acc[mB + m][nB + n], 0, 0, 0);
    __builtin_amdgcn_s_setprio(0);
  };

  ST_A(0, 0, 0); if (MIH == 4) ST_A(0, 1, 0);
  ST_B(0, 0, 0); ST_B(0, 1, 0);
  ST_A(64, 0, 1);
  ST_B(64, 1, 1);
  if (MIH == 4) { ST_A(64, 1, 1); asm volatile("s_waitcnt vmcnt(6)" ::: "memory"); }
  else          { asm volatile("s_waitcnt vmcnt(4)" ::: "memory"); }
  GBAR;

  const int nIter = nt >> 1;
  for (int it = 0; it < nIter; ++it) {
    const int k1 = (2 * it + 1) << 6;
    const int k2 = (2 * it + 2) << 6, k3 = (2 * it + 3) << 6;
    const bool h2 = (2 * it + 2) < nt, h3 = (2 * it + 3) < nt;

    LDA(0, 0); LDB(0, 0, bflo);
    ST_B(k1, 0, 1);
    GBAR; MM(bflo, 0, 0); GBAR;
    LDB(0, 1, bfhi);
    if (h2 && MIH == 4) ST_A(k2, 0, 0);
    GBAR; MM(bfhi, 0, 2); GBAR;
    LDA(0, 1);
    if (h2) ST_B(k2, 1, 0);
    GBAR; MM(bfhi, MIH, 2); GBAR;
    if (h2) ST_A(k2, (MIH == 4) ? 1 : 0, 0);
    if (h2) {
      if (MIH == 4) asm volatile("s_waitcnt vmcnt(6)" ::: "memory");
      else          asm volatile("s_waitcnt vmcnt(4)" ::: "memory");
    } else {
      asm volatile("s_waitcnt vmcnt(0)" ::: "memory");
    }
    GBAR; MM(bflo, MIH, 0); GBAR;

    LDA(1, 0); LDB(1, 0, bflo);
    if (h2) ST_B(k2, 0, 0);
    GBAR; MM(bflo, 0, 0); GBAR;
    LDB(1, 1, bfhi);
    if (h3 && MIH == 4) ST_A(k3, 0, 1);
    GBAR; MM(bfhi, 0, 2); GBAR;
    LDA(1, 1);
    if (h3) ST_B(k3, 1, 1);
    GBAR; MM(bfhi, MIH, 2); GBAR;
    if (h3) ST_A(k3, (MIH == 4) ? 1 : 0, 1);
    if (h3) {
      if (MIH == 4) asm volatile("s_waitcnt vmcnt(6)" ::: "memory");
      else          asm volatile("s_waitcnt vmcnt(4)" ::: "memory");
    } else {
      asm volatile("s_waitcnt vmcnt(0)" ::: "memory");
    }
    GBAR; MM(bflo, MIH, 0); GBAR;
  }

  // ---------------- epilogue ----------------
  if (EPI == 2 && (n0 >> 10) == 2) {
    // V block (uniform): bias-add, then LDS transpose [d][s] (pad 136) -> coalesced flush
    short* TR = (short*)LDSBUF;
    __syncthreads();
#pragma unroll
    for (int ni = 0; ni < 4; ++ni) {
      const int dloc = wc * 64 + ni * 16 + lr;          // 0..255
      const float bvs = bias3[(n0 - 2048) + dloc];
#pragma unroll
      for (int mi = 0; mi < 2 * MIH; ++mi) {
        const int sloc = wr * (MIH * 32) + mi * 16 + lg * 4;  // 0..BM-4
        sv4 pk;
#pragma unroll
        for (int j = 0; j < 4; ++j) pk[j] = f2bs(acc[mi][ni][j] + bvs);
        *(sv4*)(TR + dloc * 136 + sloc) = pk;           // b64, ~2-4 way conflicts (epilogue-only)
      }
    }
    __syncthreads();
    const int bb = m0 >> 11, s0r = m0 & 2047;
    const int dd = t >> 1, sh = (t & 1) * 64;           // 512 thr -> 256 rows x 2 halves
    const int dg = (n0 - 2048) + dd;
    const int hh = dg >> 6, dl = dg & 63;
    short* dst = D3 + ((size_t)(bb * 16 + hh) * 64 + dl) * 2048 + s0r + sh;
    if (MIH == 2) {                                      // BM=128: halves are 64 shorts
#pragma unroll
      for (int i = 0; i < 8; ++i)
        *(bv8*)(dst + i * 8) = *(const bv8*)(TR + dd * 136 + sh + i * 8);
    }
    return;
  }

#pragma unroll
  for (int ni = 0; ni < 4; ++ni) {
    const int c = n0 + wc * 64 + ni * 16 + lr;
    float bvs;
    int sel = 0, h = 0, d = 0;
    if (EPI == 2) {
      sel = c >> 10; const int cc = c & 1023;
      bvs = (sel == 0 ? bias : bias2)[cc];
      h = cc >> 6; d = cc & 63;
    } else {
      bvs = bias[c];
    }
#pragma unroll
    for (int mi = 0; mi < 2 * MIH; ++mi) {
#pragma unroll
      for (int j = 0; j < 4; ++j) {
        const int r = m0 + wr * (MIH * 32) + mi * 16 + lg * 4 + j;
        float v = acc[mi][ni][j] + bvs;
        if (EPI == 1) v = fmaxf(v, 0.f);
        if (EPI == 2) {
          const int bb = r >> 11, s = r & 2047;
          if (sel == 0) C [((size_t)(bb * 16 + h) * 2048 + s) * 64 + d] = f2bs(v);
          else          D2[((size_t)(bb * 16 + h) * 2048 + s) * 64 + d] = f2bs(v);
        } else {
          C[(size_t)r * N + c] = f2bs(v);
        }
      }
    }
  }
}

// ---------------- flash attention (R10 structure: in-reg P, depth-1 V prefetch) ----------------
// vfA issued at loop top (hidden under QKSM(0)); vfB after QKSM(0) (hidden under
// PV(vfA)+QKSM(1)). Both scoped inside the loop -> VGPR ~104, 4 waves/SIMD.
__global__ __launch_bounds__(256) void k_attn(const short* __restrict__ Qg, const short* __restrict__ Kg,
                                              const short* __restrict__ Vtg, short* __restrict__ Oc) {
  __shared__ __align__(16) short Ks[2][128 * 64];  // dbuf [s][dk] swizzled, 128B rows

  const int t = threadIdx.x, lane = t & 63, w = t >> 6;
  const int lr = lane & 15, lg = lane >> 4;
  const int bid = blockIdx.x;
  const int wid = (bid & 7) * 128 + (bid >> 3);
  const int q0 = (wid & 15) * 128;
  const int bh = wid >> 4;
  const int b = bh >> 4, h = bh & 15;
  const short* Qp = Qg + (size_t)bh * 2048 * 64;
  const short* Kp = Kg + (size_t)bh * 2048 * 64;
  const short* Vp = Vtg + (size_t)bh * 64 * 2048;

  bv8 qf[2][2];
#pragma unroll
  for (int mi = 0; mi < 2; ++mi)
#pragma unroll
    for (int kk = 0; kk < 2; ++kk)
      qf[mi][kk] = *(const bv8*)(Qp + (size_t)(q0 + w * 32 + mi * 16 + lr) * 64 + kk * 32 + lg * 8);

  f4 Oa[2][4] = {};
  float lsum[2] = {0.f, 0.f};
  const float SC = 0.125f * 1.44269504089f;
  const bool hi = lg >= 2;
  const bool xx = (lg == 1) || (lg == 2);

  auto QKSM = [&](const char* Kb, int hf, bv8 (&pf)[2][2]) {
    f4 Sa[2][4] = {};
#pragma unroll
    for (int kk = 0; kk < 2; ++kk) {
      bv8 kf[4];
#pragma unroll
      for (int nl = 0; nl < 4; ++nl) {
        const int row = (hf * 4 + nl) * 16 + lr;
        const int cb = kk * 64 + lg * 16;
        kf[nl] = *(const bv8*)(Kb + row * 128 + (cb ^ ((row & 7) << 4)));
      }
      __builtin_amdgcn_s_setprio(1);
#pragma unroll
      for (int mi = 0; mi < 2; ++mi)
#pragma unroll
        for (int nl = 0; nl < 4; ++nl)
          Sa[mi][nl] = __builtin_amdgcn_mfma_f32_16x16x32_bf16(kf[nl], qf[mi][kk], Sa[mi][nl], 0, 0, 0);
      __builtin_amdgcn_s_setprio(0);
    }
#pragma unroll
    for (int mi = 0; mi < 2; ++mi) {
      float rs = 0.f;
#pragma unroll
      for (int nl = 0; nl < 4; ++nl)
#pragma unroll
        for (int j = 0; j < 4; ++j) {
          const float p = EXP2F(Sa[mi][nl][j] * SC);
          Sa[mi][nl][j] = p;
          rs += p;
        }
      lsum[mi] += rs;
    }
#pragma unroll
    for (int k2 = 0; k2 < 2; ++k2)
#pragma unroll
      for (int mi = 0; mi < 2; ++mi) {
        const unsigned W0 = cvtpk(Sa[mi][2 * k2][0], Sa[mi][2 * k2][1]);
        const unsigned W1 = cvtpk(Sa[mi][2 * k2][2], Sa[mi][2 * k2][3]);
        const unsigned W2 = cvtpk(Sa[mi][2 * k2 + 1][0], Sa[mi][2 * k2 + 1][1]);
        const unsigned W3 = cvtpk(Sa[mi][2 * k2 + 1][2], Sa[mi][2 * k2 + 1][3]);
        const unsigned w0 = hi ? W2 : W0, w1 = hi ? W3 : W1;
        const unsigned s0 = __shfl_xor(hi ? W0 : W2, 32);
        const unsigned s1 = __shfl_xor(hi ? W1 : W3, 32);
        const unsigned t0 = __shfl_xor(xx ? w0 : s0, 16);
        const unsigned t1 = __shfl_xor(xx ? w1 : s1, 16);
        uv4 u;
        u[0] = (lg == 0) ? w0 : (lg == 2) ? s0 : t0;
        u[1] = (lg == 0) ? w1 : (lg == 2) ? s1 : t1;
        u[2] = (lg == 3) ? w0 : (lg == 1) ? s0 : t0;
        u[3] = (lg == 3) ? w1 : (lg == 1) ? s1 : t1;
        pf[k2][mi] = __builtin_bit_cast(bv8, u);
      }
  };
  auto LOADV = [&](int kt, int hf, bv8 (&vf)[2][4]) {
#pragma unroll
    for (int k2 = 0; k2 < 2; ++k2)
#pragma unroll
      for (int nO = 0; nO < 4; ++nO)
        vf[k2][nO] = *(const bv8*)(Vp + (size_t)(nO * 16 + lr) * 2048 + kt + hf * 64 + k2 * 32 + lg * 8);
  };
  auto PV = [&](bv8 (&vf)[2][4], bv8 (&pf)[2][2]) {
    __builtin_amdgcn_s_setprio(1);
#pragma unroll
    for (int k2 = 0; k2 < 2; ++k2)
#pragma unroll
      for (int mi = 0; mi < 2; ++mi)
#pragma unroll
        for (int nO = 0; nO < 4; ++nO)
          Oa[mi][nO] = __builtin_amdgcn_mfma_f32_16x16x32_bf16(vf[k2][nO], pf[k2][mi], Oa[mi][nO], 0, 0, 0);
    __builtin_amdgcn_s_setprio(0);
  };

#pragma unroll
  for (int i = 0; i < 4; ++i) {
    const int L = t * 16 + i * 4096;
    const int row = L >> 7;
    const int cbs = (L & 127) ^ ((row & 7) << 4);
    gload16(Kp + (size_t)row * 64 + (cbs >> 1), (char*)Ks[0] + L);
  }
  __syncthreads();

  int cur = 0;
  for (int kt = 0; kt < 2048; kt += 128) {
    if (kt + 128 < 2048) {
#pragma unroll
      for (int i = 0; i < 4; ++i) {
        const int L = t * 16 + i * 4096;
        const int row = L >> 7;
        const int cbs = (L & 127) ^ ((row & 7) << 4);
        gload16(Kp + (size_t)(kt + 128 + row) * 64 + (cbs >> 1), (char*)Ks[cur ^ 1] + L);
      }
    }
    const char* Kb = (const char*)Ks[cur];

    bv8 vfA[2][4], vfB[2][4], pfA[2][2], pfB[2][2];
    LOADV(kt, 0, vfA);        // issue V(hf0) early: hidden under QK(0)+SM(0)
    QKSM(Kb, 0, pfA);
    LOADV(kt, 1, vfB);        // issue V(hf1): hidden under PV(0)+QK(1)+SM(1)
    PV(vfA, pfA);
    QKSM(Kb, 1, pfB);
    PV(vfB, pfB);

    __syncthreads();
    cur ^= 1;
  }

#pragma unroll
  for (int mi = 0; mi < 2; ++mi) {
    lsum[mi] += __shfl_xor(lsum[mi], 16);
    lsum[mi] += __shfl_xor(lsum[mi], 32);
  }

#pragma unroll
  for (int mi = 0; mi < 2; ++mi) {
    const float inv = 1.f / lsum[mi];
    const int q = q0 + w * 32 + mi * 16 + lr;
#pragma unroll
    for (int nO = 0; nO < 4; ++nO) {
      sv4 o;
#pragma unroll
      for (int j = 0; j < 4; ++j) o[j] = f2bs(Oa[mi][nO][j] * inv);
      const int c = h * 64 + nO * 16 + lg * 4;
      *(sv4*)(Oc + ((size_t)b * 2048 + q) * 1024 + c) = o;
    }
  }
}

// ---------------- residual + LayerNorm (mean, unbiased std, eps on std) ----------------
template<int MODE>
__global__ __launch_bounds__(256) void k_resnorm(const short* __restrict__ a, const void* __restrict__ res,
                                                 const float* __restrict__ alpha, const float* __restrict__ beta,
                                                 void* __restrict__ out) {
  const int row = blockIdx.x;
  const int t = threadIdx.x;
  const int lane = t & 63, w = t >> 6;
  const size_t base = (size_t)row * 1024;

  const sv4 av = *(const sv4*)(a + base + t * 4);
  float v[4];
  if (MODE == 0) {
    const float4 rv = *(const float4*)((const float*)res + base + t * 4);
    v[0] = bs2f(av[0]) + rv.x; v[1] = bs2f(av[1]) + rv.y;
    v[2] = bs2f(av[2]) + rv.z; v[3] = bs2f(av[3]) + rv.w;
  } else {
    const sv4 rv = *(const sv4*)((const short*)res + base + t * 4);
#pragma unroll
    for (int i = 0; i < 4; ++i) v[i] = bs2f(av[i]) + bs2f(rv[i]);
  }
  float s = v[0] + v[1] + v[2] + v[3];
  float sq = v[0] * v[0] + v[1] * v[1] + v[2] * v[2] + v[3] * v[3];
#pragma unroll
  for (int m = 1; m < 64; m <<= 1) { s += __shfl_xor(s, m); sq += __shfl_xor(sq, m); }
  __shared__ float red[8];
  if (lane == 0) { red[w] = s; red[w + 4] = sq; }
  __syncthreads();
  s = red[0] + red[1] + red[2] + red[3];
  sq = red[4] + red[5] + red[6] + red[7];
  const float mean = s * (1.f / 1024.f);
  const float var = (sq - 1024.f * mean * mean) * (1.f / 1023.f);   // ddof=1
  const float inv = 1.f / (sqrtf(fmaxf(var, 0.f)) + 1e-6f);          // eps added to std
  const float4 al = *(const float4*)(alpha + t * 4);
  const float4 be = *(const float4*)(beta + t * 4);
  float y[4];
  y[0] = al.x * (v[0] - mean) * inv + be.x;
  y[1] = al.y * (v[1] - mean) * inv + be.y;
  y[2] = al.z * (v[2] - mean) * inv + be.z;
  y[3] = al.w * (v[3] - mean) * inv + be.w;
  if (MODE == 0) {
    sv4 o; o[0] = f2bs(y[0]); o[1] = f2bs(y[1]); o[2] = f2bs(y[2]); o[3] = f2bs(y[3]);
    *(sv4*)((short*)out + base + t * 4) = o;
  } else {
    *(float4*)((float*)out + base + t * 4) = make_float4(y[0], y[1], y[2], y[3]);
  }
}

extern "C" void kernel_launch(void* const* d_in, const int* in_sizes, int n_in,
                              void* d_out, int out_size, void* d_ws, size_t ws_size,
                              hipStream_t stream) {
  const float* x   = (const float*)d_in[0];
  const float* Wq  = (const float*)d_in[1];
  const float* bq  = (const float*)d_in[2];
  const float* Wk  = (const float*)d_in[3];
  const float* bk  = (const float*)d_in[4];
  const float* Wv  = (const float*)d_in[5];
  const float* bv  = (const float*)d_in[6];
  const float* Wo  = (const float*)d_in[7];
  const float* bo  = (const float*)d_in[8];
  const float* al1 = (const float*)d_in[9];
  const float* bi1 = (const float*)d_in[10];
  const float* al2 = (const float*)d_in[11];
  const float* bi2 = (const float*)d_in[12];
  const float* W1  = (const float*)d_in[13];
  const float* b1  = (const float*)d_in[14];
  const float* W2  = (const float*)d_in[15];
  const float* b2  = (const float*)d_in[16];

  if (ws_size < (size_t)136 * 1024 * 1024) return;  // need 136MB scratch

  char* ws = (char*)d_ws;
  short* xb  = (short*)(ws);                   // 16MB, dead after QKV
  short* Qb  = (short*)(ws + (16ll << 20));    // 16MB
  short* Kb  = (short*)(ws + (32ll << 20));    // 16MB
  short* Vtb = (short*)(ws + (48ll << 20));    // 16MB
  short* Hb  = (short*)(ws);                   // 64MB: reuses xb+Q+K+Vt after attention
  short* Wqt = (short*)(ws + (64ll << 20));    // [3072][1024] contiguous with Wkt/Wvt
  short* Wkt = (short*)(ws + (66ll << 20));
  short* Wvt = (short*)(ws + (68ll << 20));
  short* Wot = (short*)(ws + (70ll << 20));
  short* W1t = (short*)(ws + (72ll << 20));    // 8MB
  short* W2t = (short*)(ws + (80ll << 20));    // 8MB
  short* Cc  = (short*)(ws + (88ll << 20));    // 16MB
  short* AOb = (short*)(ws + (104ll << 20));   // 16MB, reused for FFb
  short* N1b = (short*)(ws + (120ll << 20));   // 16MB
  short* FFb = (short*)(ws + (104ll << 20));

  // fused prep (1 launch replaces 7)
  k_prep<<<20480, 256, 0, stream>>>(x, xb, Wq, Wqt, Wk, Wkt, Wv, Wvt, Wo, Wot, W1, W1t, W2, W2t);

  // fused QKV: 8192x3072 @ K=1024, 128x256 tiles -> grid 768
  k_gemm8p<2, 2><<<768, 512, 0, stream>>>(xb, Wqt, bq, bk, bv, Qb, Kb, Vtb, 8192, 3072, 1024, 12);

  // attention -> concat
  k_attn<<<1024, 256, 0, stream>>>(Qb, Kb, Vtb, Cc);

  // output proj: 8192x1024, 128x256 tiles -> grid 256
  k_gemm8p<0, 2><<<256, 512, 0, stream>>>(Cc, Wot, bo, nullptr, nullptr, AOb, nullptr, nullptr,
                                          8192, 1024, 1024, 4);
  k_resnorm<0><<<8192, 256, 0, stream>>>(AOb, x, al1, bi1, N1b);

  // FFN1: 8192x4096 relu, 256x256 tiles -> grid 512
  k_gemm8p<1, 4><<<512, 512, 0, stream>>>(N1b, W1t, b1, nullptr, nullptr, Hb, nullptr, nullptr,
                                          8192, 4096, 1024, 16);
  // FFN2: 8192x1024 @ K=4096, 128x256 tiles -> grid 256
  k_gemm8p<0, 2><<<256, 512, 0, stream>>>(Hb, W2t, b2, nullptr, nullptr, FFb, nullptr, nullptr,
                                          8192, 1024, 4096, 4);
  k_resnorm<1><<<8192, 256, 0, stream>>>(FFb, N1b, al2, bi2, (float*)d_out);
}

// Round 13
// 406.818 us; speedup vs baseline: 1.2762x; 1.0108x over previous
//
#include <hip/hip_runtime.h>
#include <hip/hip_bf16.h>
#include <stdint.h>

typedef __attribute__((ext_vector_type(8))) short bv8;   // 8 x bf16 (MFMA A/B frag)
typedef __attribute__((ext_vector_type(4))) short sv4;   // 4 x bf16
typedef __attribute__((ext_vector_type(4))) float f4;    // MFMA C/D frag
typedef __attribute__((ext_vector_type(4))) unsigned uv4;

#define LDS_AS __attribute__((address_space(3)))
#define GLB_AS __attribute__((address_space(1)))

#if __has_builtin(__builtin_amdgcn_exp2f)
#define EXP2F(x) __builtin_amdgcn_exp2f(x)
#else
#define EXP2F(x) exp2f(x)
#endif

#define GBAR __builtin_amdgcn_s_barrier()

__device__ __forceinline__ void gload16(const void* g, void* l) {
  __builtin_amdgcn_global_load_lds((GLB_AS void*)(g), (LDS_AS void*)(l), 16, 0, 0);
}

__device__ __forceinline__ short f2bs(float x) {
  return __builtin_bit_cast(short, __float2bfloat16(x));
}
__device__ __forceinline__ float bs2f(short s) {
  unsigned u = ((unsigned)(unsigned short)s) << 16;
  return __builtin_bit_cast(float, u);
}
__device__ __forceinline__ unsigned cvtpk(float lo, float hi) {
  unsigned r;
  asm("v_cvt_pk_bf16_f32 %0, %1, %2" : "=v"(r) : "v"(lo), "v"(hi));
  return r;
}

// ---------------- fused prep: x cvt + all 6 weight transposes in ONE launch ----------------
__global__ __launch_bounds__(256) void k_prep(const float* __restrict__ x, short* __restrict__ xb,
                                              const float* __restrict__ Wq, short* __restrict__ Wqt,
                                              const float* __restrict__ Wk, short* __restrict__ Wkt,
                                              const float* __restrict__ Wv, short* __restrict__ Wvt,
                                              const float* __restrict__ Wo, short* __restrict__ Wot,
                                              const float* __restrict__ W1, short* __restrict__ W1t,
                                              const float* __restrict__ W2, short* __restrict__ W2t) {
  const int bid = blockIdx.x;
  if (bid < 8192) {
    const int i = (bid * 256 + threadIdx.x) * 4;
    const float4 v = *(const float4*)(x + i);
    sv4 o; o[0] = f2bs(v.x); o[1] = f2bs(v.y); o[2] = f2bs(v.z); o[3] = f2bs(v.w);
    *(sv4*)(xb + i) = o;
    return;
  }
  const float* W; short* Wt; int K, N, l;
  if (bid < 12288) {
    l = (bid - 8192) & 1023; K = 1024; N = 1024;
    const int sel = (bid - 8192) >> 10;
    W  = sel == 0 ? Wq  : sel == 1 ? Wk  : sel == 2 ? Wv  : Wo;
    Wt = sel == 0 ? Wqt : sel == 1 ? Wkt : sel == 2 ? Wvt : Wot;
  } else if (bid < 16384) {
    l = bid - 12288; K = 1024; N = 4096; W = W1; Wt = W1t;
  } else {
    l = bid - 16384; K = 4096; N = 1024; W = W2; Wt = W2t;
  }
  const int nb = N >> 5;
  const int n0 = (l % nb) * 32, k0 = (l / nb) * 32;
  __shared__ float tile[32][33];
  const int tx = threadIdx.x & 31, ty = threadIdx.x >> 5;
#pragma unroll
  for (int i = 0; i < 32; i += 8)
    tile[ty + i][tx] = W[(size_t)(k0 + ty + i) * N + n0 + tx];
  __syncthreads();
#pragma unroll
  for (int i = 0; i < 32; i += 8)
    Wt[(size_t)(n0 + ty + i) * K + k0 + tx] = f2bs(tile[tx][ty + i]);
}

// ======== 8-phase GEMM (T2+T3+T4+T5): BMxBN tile, BN=256, BM=MIH*64 ========
// EPI: 0 plain bf16, 1 relu bf16, 2 QKV (sel uniform per block; V-blocks flush via
// LDS transpose -> coalesced 16B stores instead of 2B stride-4KB scatter).
template<int EPI, int MIH>
__global__ __launch_bounds__(512) void k_gemm8p(
    const short* __restrict__ A, const short* __restrict__ Bt,
    const float* __restrict__ bias, const float* __restrict__ bias2, const float* __restrict__ bias3,
    short* __restrict__ C, short* __restrict__ D2, short* __restrict__ D3,
    int M, int N, int K, int nbx) {
  constexpr int BM = MIH * 64;
  constexpr int HOFF = (MIH == 4) ? 16384 : 4096;
  constexpr int SBOFF = 2 * BM * 128;               // bytes: SA region size
  __shared__ __align__(16) char LDSBUF[SBOFF + 65536];

  const int t = threadIdx.x;
  const int lane = t & 63, w = t >> 6;
  const int wr = w >> 2, wc = w & 3;
  const int lr = lane & 15, lg = lane >> 4;
  const int cpx = gridDim.x >> 3;
  const int bid = blockIdx.x;
  const int wid = (bid & 7) * cpx + (bid >> 3);
  const int by = wid / nbx, bx = wid % nbx;
  const int m0 = by * BM, n0 = bx * 256;
  const int nt = K >> 6;
  const int swz = ((t >> 3) & 7) << 4;
  const int rbyte0 = (lg * 16) ^ ((lr & 7) << 4);
  const int rbyte1 = (64 + lg * 16) ^ ((lr & 7) << 4);

  auto SAb = [&](int buf) -> char* { return LDSBUF + buf * (BM * 128); };
  auto SBb = [&](int buf) -> char* { return LDSBUF + SBOFF + buf * 32768; };

  auto ST_A = [&](int k0, int half, int buf) {
#pragma unroll
    for (int i = 0; i < 2; ++i) {
      const int L = t * 16 + i * 8192;
      const int cbs = (L & 127) ^ swz;
      const int grow = (MIH == 4) ? (m0 + i * 128 + half * 64 + (t >> 3))
                                  : (m0 + i * 64 + (t >> 3));
      gload16(A + (size_t)grow * K + k0 + (cbs >> 1),
              SAb(buf) + (MIH == 4 ? half * 16384 : 0) + L);
    }
  };
  auto ST_B = [&](int k0, int half, int buf) {
#pragma unroll
    for (int i = 0; i < 2; ++i) {
      const int L = t * 16 + i * 8192;
      const int rr = (t >> 3) + i * 64;
      const int cbs = (L & 127) ^ swz;
      const int grow = n0 + (rr >> 5) * 64 + half * 32 + (rr & 31);
      gload16(Bt + (size_t)grow * K + k0 + (cbs >> 1),
              SBb(buf) + half * 16384 + L);
    }
  };

  f4 acc[2 * MIH][4] = {};
  bv8 af[MIH][2], bflo[2][2], bfhi[2][2];

  auto LDA = [&](int buf, int half) {
    const char* base = SAb(buf) + half * HOFF + wr * 8192;
#pragma unroll
    for (int m = 0; m < MIH; ++m) {
      af[m][0] = *(const bv8*)(base + (m * 16 + lr) * 128 + rbyte0);
      af[m][1] = *(const bv8*)(base + (m * 16 + lr) * 128 + rbyte1);
    }
  };
  auto LDB = [&](int buf, int half, bv8 (&bf)[2][2]) {
    const char* base = SBb(buf) + half * 16384 + wc * 4096;
#pragma unroll
    for (int n = 0; n < 2; ++n) {
      bf[n][0] = *(const bv8*)(base + (n * 16 + lr) * 128 + rbyte0);
      bf[n][1] = *(const bv8*)(base + (n * 16 + lr) * 128 + rbyte1);
    }
  };
  auto MM = [&](bv8 (&bf)[2][2], int mB, int nB) {
    __builtin_amdgcn_s_setprio(1);
#pragma unroll
    for (int kk = 0; kk < 2; ++kk)
#pragma unroll
      for (int m = 0; m < MIH; ++m)
#pragma unroll
        for (int n = 0; n < 2; ++n)
          acc[mB + m][nB + n] = __builtin_amdgcn_mfma_f32_16x16x32_bf16(
              af[m][kk], bf[n][kk], acc[mB + m][nB + n], 0, 0, 0);
    __builtin_amdgcn_s_setprio(0);
  };

  ST_A(0, 0, 0); if (MIH == 4) ST_A(0, 1, 0);
  ST_B(0, 0, 0); ST_B(0, 1, 0);
  ST_A(64, 0, 1);
  ST_B(64, 1, 1);
  if (MIH == 4) { ST_A(64, 1, 1); asm volatile("s_waitcnt vmcnt(6)" ::: "memory"); }
  else          { asm volatile("s_waitcnt vmcnt(4)" ::: "memory"); }
  GBAR;

  const int nIter = nt >> 1;
  for (int it = 0; it < nIter; ++it) {
    const int k1 = (2 * it + 1) << 6;
    const int k2 = (2 * it + 2) << 6, k3 = (2 * it + 3) << 6;
    const bool h2 = (2 * it + 2) < nt, h3 = (2 * it + 3) < nt;

    LDA(0, 0); LDB(0, 0, bflo);
    ST_B(k1, 0, 1);
    GBAR; MM(bflo, 0, 0); GBAR;
    LDB(0, 1, bfhi);
    if (h2 && MIH == 4) ST_A(k2, 0, 0);
    GBAR; MM(bfhi, 0, 2); GBAR;
    LDA(0, 1);
    if (h2) ST_B(k2, 1, 0);
    GBAR; MM(bfhi, MIH, 2); GBAR;
    if (h2) ST_A(k2, (MIH == 4) ? 1 : 0, 0);
    if (h2) {
      if (MIH == 4) asm volatile("s_waitcnt vmcnt(6)" ::: "memory");
      else          asm volatile("s_waitcnt vmcnt(4)" ::: "memory");
    } else {
      asm volatile("s_waitcnt vmcnt(0)" ::: "memory");
    }
    GBAR; MM(bflo, MIH, 0); GBAR;

    LDA(1, 0); LDB(1, 0, bflo);
    if (h2) ST_B(k2, 0, 0);
    GBAR; MM(bflo, 0, 0); GBAR;
    LDB(1, 1, bfhi);
    if (h3 && MIH == 4) ST_A(k3, 0, 1);
    GBAR; MM(bfhi, 0, 2); GBAR;
    LDA(1, 1);
    if (h3) ST_B(k3, 1, 1);
    GBAR; MM(bfhi, MIH, 2); GBAR;
    if (h3) ST_A(k3, (MIH == 4) ? 1 : 0, 1);
    if (h3) {
      if (MIH == 4) asm volatile("s_waitcnt vmcnt(6)" ::: "memory");
      else          asm volatile("s_waitcnt vmcnt(4)" ::: "memory");
    } else {
      asm volatile("s_waitcnt vmcnt(0)" ::: "memory");
    }
    GBAR; MM(bflo, MIH, 0); GBAR;
  }

  // ---------------- epilogue ----------------
  if (EPI == 2 && (n0 >> 10) == 2) {
    // V block (uniform): bias-add, then LDS transpose [d][s] (pad 136) -> coalesced flush
    short* TR = (short*)LDSBUF;
    __syncthreads();
#pragma unroll
    for (int ni = 0; ni < 4; ++ni) {
      const int dloc = wc * 64 + ni * 16 + lr;          // 0..255
      const float bvs = bias3[(n0 - 2048) + dloc];
#pragma unroll
      for (int mi = 0; mi < 2 * MIH; ++mi) {
        const int sloc = wr * (MIH * 32) + mi * 16 + lg * 4;  // 0..BM-4
        sv4 pk;
#pragma unroll
        for (int j = 0; j < 4; ++j) pk[j] = f2bs(acc[mi][ni][j] + bvs);
        *(sv4*)(TR + dloc * 136 + sloc) = pk;           // b64, ~2-4 way conflicts (epilogue-only)
      }
    }
    __syncthreads();
    const int bb = m0 >> 11, s0r = m0 & 2047;
    const int dd = t >> 1, sh = (t & 1) * 64;           // 512 thr -> 256 rows x 2 halves
    const int dg = (n0 - 2048) + dd;
    const int hh = dg >> 6, dl = dg & 63;
    short* dst = D3 + ((size_t)(bb * 16 + hh) * 64 + dl) * 2048 + s0r + sh;
    if (MIH == 2) {                                      // BM=128: halves are 64 shorts
#pragma unroll
      for (int i = 0; i < 8; ++i)
        *(bv8*)(dst + i * 8) = *(const bv8*)(TR + dd * 136 + sh + i * 8);
    }
    return;
  }

#pragma unroll
  for (int ni = 0; ni < 4; ++ni) {
    const int c = n0 + wc * 64 + ni * 16 + lr;
    float bvs;
    int sel = 0, h = 0, d = 0;
    if (EPI == 2) {
      sel = c >> 10; const int cc = c & 1023;
      bvs = (sel == 0 ? bias : bias2)[cc];
      h = cc >> 6; d = cc & 63;
    } else {
      bvs = bias[c];
    }
#pragma unroll
    for (int mi = 0; mi < 2 * MIH; ++mi) {
#pragma unroll
      for (int j = 0; j < 4; ++j) {
        const int r = m0 + wr * (MIH * 32) + mi * 16 + lg * 4 + j;
        float v = acc[mi][ni][j] + bvs;
        if (EPI == 1) v = fmaxf(v, 0.f);
        if (EPI == 2) {
          const int bb = r >> 11, s = r & 2047;
          if (sel == 0) C [((size_t)(bb * 16 + h) * 2048 + s) * 64 + d] = f2bs(v);
          else          D2[((size_t)(bb * 16 + h) * 2048 + s) * 64 + d] = f2bs(v);
        } else {
          C[(size_t)r * N + c] = f2bs(v);
        }
      }
    }
  }
}

// ---------------- flash attention: in-reg P, serialized V liveness ----------------
// Single vf buffer; order LOADV(0)->QKSM(0)->PV(0)->LOADV(1)->QKSM(1)->PV(1).
// vf(hf0) and vf(hf1) never co-live (-32 peak regs vs R12) -> target 3 waves/SIMD.
// LOADV(1) still hidden under QKSM(1) (~400cyc >> L2 latency; V is L2-resident).
__global__ __launch_bounds__(256) void k_attn(const short* __restrict__ Qg, const short* __restrict__ Kg,
                                              const short* __restrict__ Vtg, short* __restrict__ Oc) {
  __shared__ __align__(16) short Ks[2][128 * 64];  // dbuf [s][dk] swizzled, 128B rows

  const int t = threadIdx.x, lane = t & 63, w = t >> 6;
  const int lr = lane & 15, lg = lane >> 4;
  const int bid = blockIdx.x;
  const int wid = (bid & 7) * 128 + (bid >> 3);
  const int q0 = (wid & 15) * 128;
  const int bh = wid >> 4;
  const int b = bh >> 4, h = bh & 15;
  const short* Qp = Qg + (size_t)bh * 2048 * 64;
  const short* Kp = Kg + (size_t)bh * 2048 * 64;
  const short* Vp = Vtg + (size_t)bh * 64 * 2048;

  bv8 qf[2][2];
#pragma unroll
  for (int mi = 0; mi < 2; ++mi)
#pragma unroll
    for (int kk = 0; kk < 2; ++kk)
      qf[mi][kk] = *(const bv8*)(Qp + (size_t)(q0 + w * 32 + mi * 16 + lr) * 64 + kk * 32 + lg * 8);

  f4 Oa[2][4] = {};
  float lsum[2] = {0.f, 0.f};
  const float SC = 0.125f * 1.44269504089f;
  const bool hi = lg >= 2;
  const bool xx = (lg == 1) || (lg == 2);

  auto QKSM = [&](const char* Kb, int hf, bv8 (&pf)[2][2]) {
    f4 Sa[2][4] = {};
#pragma unroll
    for (int kk = 0; kk < 2; ++kk) {
      bv8 kf[4];
#pragma unroll
      for (int nl = 0; nl < 4; ++nl) {
        const int row = (hf * 4 + nl) * 16 + lr;
        const int cb = kk * 64 + lg * 16;
        kf[nl] = *(const bv8*)(Kb + row * 128 + (cb ^ ((row & 7) << 4)));
      }
      __builtin_amdgcn_s_setprio(1);
#pragma unroll
      for (int mi = 0; mi < 2; ++mi)
#pragma unroll
        for (int nl = 0; nl < 4; ++nl)
          Sa[mi][nl] = __builtin_amdgcn_mfma_f32_16x16x32_bf16(kf[nl], qf[mi][kk], Sa[mi][nl], 0, 0, 0);
      __builtin_amdgcn_s_setprio(0);
    }
#pragma unroll
    for (int mi = 0; mi < 2; ++mi) {
      float rs = 0.f;
#pragma unroll
      for (int nl = 0; nl < 4; ++nl)
#pragma unroll
        for (int j = 0; j < 4; ++j) {
          const float p = EXP2F(Sa[mi][nl][j] * SC);
          Sa[mi][nl][j] = p;
          rs += p;
        }
      lsum[mi] += rs;
    }
#pragma unroll
    for (int k2 = 0; k2 < 2; ++k2)
#pragma unroll
      for (int mi = 0; mi < 2; ++mi) {
        const unsigned W0 = cvtpk(Sa[mi][2 * k2][0], Sa[mi][2 * k2][1]);
        const unsigned W1 = cvtpk(Sa[mi][2 * k2][2], Sa[mi][2 * k2][3]);
        const unsigned W2 = cvtpk(Sa[mi][2 * k2 + 1][0], Sa[mi][2 * k2 + 1][1]);
        const unsigned W3 = cvtpk(Sa[mi][2 * k2 + 1][2], Sa[mi][2 * k2 + 1][3]);
        const unsigned w0 = hi ? W2 : W0, w1 = hi ? W3 : W1;
        const unsigned s0 = __shfl_xor(hi ? W0 : W2, 32);
        const unsigned s1 = __shfl_xor(hi ? W1 : W3, 32);
        const unsigned t0 = __shfl_xor(xx ? w0 : s0, 16);
        const unsigned t1 = __shfl_xor(xx ? w1 : s1, 16);
        uv4 u;
        u[0] = (lg == 0) ? w0 : (lg == 2) ? s0 : t0;
        u[1] = (lg == 0) ? w1 : (lg == 2) ? s1 : t1;
        u[2] = (lg == 3) ? w0 : (lg == 1) ? s0 : t0;
        u[3] = (lg == 3) ? w1 : (lg == 1) ? s1 : t1;
        pf[k2][mi] = __builtin_bit_cast(bv8, u);
      }
  };
  auto LOADV = [&](int kt, int hf, bv8 (&vf)[2][4]) {
#pragma unroll
    for (int k2 = 0; k2 < 2; ++k2)
#pragma unroll
      for (int nO = 0; nO < 4; ++nO)
        vf[k2][nO] = *(const bv8*)(Vp + (size_t)(nO * 16 + lr) * 2048 + kt + hf * 64 + k2 * 32 + lg * 8);
  };
  auto PV = [&](bv8 (&vf)[2][4], bv8 (&pf)[2][2]) {
    __builtin_amdgcn_s_setprio(1);
#pragma unroll
    for (int k2 = 0; k2 < 2; ++k2)
#pragma unroll
      for (int mi = 0; mi < 2; ++mi)
#pragma unroll
        for (int nO = 0; nO < 4; ++nO)
          Oa[mi][nO] = __builtin_amdgcn_mfma_f32_16x16x32_bf16(vf[k2][nO], pf[k2][mi], Oa[mi][nO], 0, 0, 0);
    __builtin_amdgcn_s_setprio(0);
  };

#pragma unroll
  for (int i = 0; i < 4; ++i) {
    const int L = t * 16 + i * 4096;
    const int row = L >> 7;
    const int cbs = (L & 127) ^ ((row & 7) << 4);
    gload16(Kp + (size_t)row * 64 + (cbs >> 1), (char*)Ks[0] + L);
  }
  __syncthreads();

  int cur = 0;
  for (int kt = 0; kt < 2048; kt += 128) {
    if (kt + 128 < 2048) {
#pragma unroll
      for (int i = 0; i < 4; ++i) {
        const int L = t * 16 + i * 4096;
        const int row = L >> 7;
        const int cbs = (L & 127) ^ ((row & 7) << 4);
        gload16(Kp + (size_t)(kt + 128 + row) * 64 + (cbs >> 1), (char*)Ks[cur ^ 1] + L);
      }
    }
    const char* Kb = (const char*)Ks[cur];

    bv8 vf[2][4], pfA[2][2], pfB[2][2];
    LOADV(kt, 0, vf);          // hidden under QKSM(0)
    QKSM(Kb, 0, pfA);
    PV(vf, pfA);               // vf(hf0) dies here
    LOADV(kt, 1, vf);          // reuse same regs; hidden under QKSM(1)
    QKSM(Kb, 1, pfB);
    PV(vf, pfB);

    __syncthreads();
    cur ^= 1;
  }

#pragma unroll
  for (int mi = 0; mi < 2; ++mi) {
    lsum[mi] += __shfl_xor(lsum[mi], 16);
    lsum[mi] += __shfl_xor(lsum[mi], 32);
  }

#pragma unroll
  for (int mi = 0; mi < 2; ++mi) {
    const float inv = 1.f / lsum[mi];
    const int q = q0 + w * 32 + mi * 16 + lr;
#pragma unroll
    for (int nO = 0; nO < 4; ++nO) {
      sv4 o;
#pragma unroll
      for (int j = 0; j < 4; ++j) o[j] = f2bs(Oa[mi][nO][j] * inv);
      const int c = h * 64 + nO * 16 + lg * 4;
      *(sv4*)(Oc + ((size_t)b * 2048 + q) * 1024 + c) = o;
    }
  }
}

// ---------------- residual + LayerNorm (mean, unbiased std, eps on std) ----------------
template<int MODE>
__global__ __launch_bounds__(256) void k_resnorm(const short* __restrict__ a, const void* __restrict__ res,
                                                 const float* __restrict__ alpha, const float* __restrict__ beta,
                                                 void* __restrict__ out) {
  const int row = blockIdx.x;
  const int t = threadIdx.x;
  const int lane = t & 63, w = t >> 6;
  const size_t base = (size_t)row * 1024;

  const sv4 av = *(const sv4*)(a + base + t * 4);
  float v[4];
  if (MODE == 0) {
    const float4 rv = *(const float4*)((const float*)res + base + t * 4);
    v[0] = bs2f(av[0]) + rv.x; v[1] = bs2f(av[1]) + rv.y;
    v[2] = bs2f(av[2]) + rv.z; v[3] = bs2f(av[3]) + rv.w;
  } else {
    const sv4 rv = *(const sv4*)((const short*)res + base + t * 4);
#pragma unroll
    for (int i = 0; i < 4; ++i) v[i] = bs2f(av[i]) + bs2f(rv[i]);
  }
  float s = v[0] + v[1] + v[2] + v[3];
  float sq = v[0] * v[0] + v[1] * v[1] + v[2] * v[2] + v[3] * v[3];
#pragma unroll
  for (int m = 1; m < 64; m <<= 1) { s += __shfl_xor(s, m); sq += __shfl_xor(sq, m); }
  __shared__ float red[8];
  if (lane == 0) { red[w] = s; red[w + 4] = sq; }
  __syncthreads();
  s = red[0] + red[1] + red[2] + red[3];
  sq = red[4] + red[5] + red[6] + red[7];
  const float mean = s * (1.f / 1024.f);
  const float var = (sq - 1024.f * mean * mean) * (1.f / 1023.f);   // ddof=1
  const float inv = 1.f / (sqrtf(fmaxf(var, 0.f)) + 1e-6f);          // eps added to std
  const float4 al = *(const float4*)(alpha + t * 4);
  const float4 be = *(const float4*)(beta + t * 4);
  float y[4];
  y[0] = al.x * (v[0] - mean) * inv + be.x;
  y[1] = al.y * (v[1] - mean) * inv + be.y;
  y[2] = al.z * (v[2] - mean) * inv + be.z;
  y[3] = al.w * (v[3] - mean) * inv + be.w;
  if (MODE == 0) {
    sv4 o; o[0] = f2bs(y[0]); o[1] = f2bs(y[1]); o[2] = f2bs(y[2]); o[3] = f2bs(y[3]);
    *(sv4*)((short*)out + base + t * 4) = o;
  } else {
    *(float4*)((float*)out + base + t * 4) = make_float4(y[0], y[1], y[2], y[3]);
  }
}

extern "C" void kernel_launch(void* const* d_in, const int* in_sizes, int n_in,
                              void* d_out, int out_size, void* d_ws, size_t ws_size,
                              hipStream_t stream) {
  const float* x   = (const float*)d_in[0];
  const float* Wq  = (const float*)d_in[1];
  const float* bq  = (const float*)d_in[2];
  const float* Wk  = (const float*)d_in[3];
  const float* bk  = (const float*)d_in[4];
  const float* Wv  = (const float*)d_in[5];
  const float* bv  = (const float*)d_in[6];
  const float* Wo  = (const float*)d_in[7];
  const float* bo  = (const float*)d_in[8];
  const float* al1 = (const float*)d_in[9];
  const float* bi1 = (const float*)d_in[10];
  const float* al2 = (const float*)d_in[11];
  const float* bi2 = (const float*)d_in[12];
  const float* W1  = (const float*)d_in[13];
  const float* b1  = (const float*)d_in[14];
  const float* W2  = (const float*)d_in[15];
  const float* b2  = (const float*)d_in[16];

  if (ws_size < (size_t)136 * 1024 * 1024) return;  // need 136MB scratch

  char* ws = (char*)d_ws;
  short* xb  = (short*)(ws);                   // 16MB, dead after QKV
  short* Qb  = (short*)(ws + (16ll << 20));    // 16MB
  short* Kb  = (short*)(ws + (32ll << 20));    // 16MB
  short* Vtb = (short*)(ws + (48ll << 20));    // 16MB
  short* Hb  = (short*)(ws);                   // 64MB: reuses xb+Q+K+Vt after attention
  short* Wqt = (short*)(ws + (64ll << 20));    // [3072][1024] contiguous with Wkt/Wvt
  short* Wkt = (short*)(ws + (66ll << 20));
  short* Wvt = (short*)(ws + (68ll << 20));
  short* Wot = (short*)(ws + (70ll << 20));
  short* W1t = (short*)(ws + (72ll << 20));    // 8MB
  short* W2t = (short*)(ws + (80ll << 20));    // 8MB
  short* Cc  = (short*)(ws + (88ll << 20));    // 16MB
  short* AOb = (short*)(ws + (104ll << 20));   // 16MB, reused for FFb
  short* N1b = (short*)(ws + (120ll << 20));   // 16MB
  short* FFb = (short*)(ws + (104ll << 20));

  // fused prep (1 launch replaces 7)
  k_prep<<<20480, 256, 0, stream>>>(x, xb, Wq, Wqt, Wk, Wkt, Wv, Wvt, Wo, Wot, W1, W1t, W2, W2t);

  // fused QKV: 8192x3072 @ K=1024, 128x256 tiles -> grid 768
  k_gemm8p<2, 2><<<768, 512, 0, stream>>>(xb, Wqt, bq, bk, bv, Qb, Kb, Vtb, 8192, 3072, 1024, 12);

  // attention -> concat
  k_attn<<<1024, 256, 0, stream>>>(Qb, Kb, Vtb, Cc);

  // output proj: 8192x1024, 128x256 tiles -> grid 256
  k_gemm8p<0, 2><<<256, 512, 0, stream>>>(Cc, Wot, bo, nullptr, nullptr, AOb, nullptr, nullptr,
                                          8192, 1024, 1024, 4);
  k_resnorm<0><<<8192, 256, 0, stream>>>(AOb, x, al1, bi1, N1b);

  // FFN1: 8192x4096 relu, 256x256 tiles -> grid 512
  k_gemm8p<1, 4><<<512, 512, 0, stream>>>(N1b, W1t, b1, nullptr, nullptr, Hb, nullptr, nullptr,
                                          8192, 4096, 1024, 16);
  // FFN2: 8192x1024 @ K=4096, 128x256 tiles -> grid 256
  k_gemm8p<0, 2><<<256, 512, 0, stream>>>(Hb, W2t, b2, nullptr, nullptr, FFb, nullptr, nullptr,
                                          8192, 1024, 4096, 4);
  k_resnorm<1><<<8192, 256, 0, stream>>>(FFb, N1b, al2, bi2, (float*)d_out);
}